// Round 1
// baseline (175.443 us; speedup 1.0000x reference)
//
#include <hip/hip_runtime.h>
#include <hip/hip_bf16.h>
#include <hip/hip_fp16.h>

#define N_NODES  100000
#define N_RADIAL 16
#define N_CONICAL 16

#define NPB    256                                   // nodes per bucket
#define NBKT   ((N_NODES + NPB - 1) / NPB)           // 391 buckets
#define NBLK_A 500                                   // binfuse scatter blocks (2/CU tail)
#define BTHR   512                                   // binfuse block threads
#define CHUNK  6400                                  // edges per scatter block (exact: 500*6400=3.2M)
#define SUBCAP 64                                    // per-(block,bucket) sub-run cap
                                                     // mean 16.4, sigma 4.05 -> +11.7σ, P(ovf)~6e-18/cell
#define BKTSTRIDE (NBLK_A * SUBCAP)                  // 32000 slots per bucket
#define CAP    10240                                 // compacted bucket cap in LDS (mean 8192 + 22σ)

// ---------------------------------------------------------------------------
// A. Fused bin+prep. Blocks 0..499: single-pass scatter into fixed-capacity
//    per-(block,bucket) sub-runs — 1 LDS cursor atomic + 1 line-dense write
//    per edge. R11: 500 blocks (2/CU in the scatter tail, was 1/CU) and
//    int4 edge loads giving 4 independent atomic->store chains per thread
//    (attacks the 47µs latency-bound tail: VALUBusy 2.9%, Occ 22.9%).
//    Block 500: W1/W2 transposes. Blocks 501..: xcon f16 pack, one
//    float4 -> uint2 per thread (halved block count vs R10).
// ---------------------------------------------------------------------------
__global__ __launch_bounds__(BTHR) void binfuse_kernel(
    const int* __restrict__ idx, const float* __restrict__ x,
    __half2* __restrict__ xcon2,
    const float* __restrict__ W1, const float* __restrict__ W2,
    float* __restrict__ W1t, float* __restrict__ W2t,
    unsigned int* __restrict__ binned, int* __restrict__ cnts,
    int chunk, int total, int E) {
    int b = blockIdx.x, tid = threadIdx.x;
    if (b >= NBLK_A) {
        int pb = b - NBLK_A;
        if (pb == 0) {                       // weight transposes (4096 each)
            for (int i = tid; i < 4096; i += BTHR) {
                int c = i >> 7, k = i & 127;
                W1t[k * 32 + c] = W1[i];     // W1[c][k] -> W1t[k][c]
                int kk = i >> 5, o = i & 31;
                W2t[o * 128 + kk] = W2[i];   // W2[k][o] -> W2t[o][k]
            }
        } else {                             // xcon pack: one float4 -> uint2/thread
            int t = (pb - 1) * BTHR + tid;
            if (t < N_NODES * 4) {
                int n = t >> 2, p = t & 3;
                float4 v = *((const float4*)(x + (size_t)n * 32 + 16) + p);
                __half2 h0 = __floats2half2_rn(v.x, v.y);
                __half2 h1 = __floats2half2_rn(v.z, v.w);
                uint2 st;
                st.x = *(unsigned int*)&h0; st.y = *(unsigned int*)&h1;
                *(uint2*)(xcon2 + 2 * t) = st;
            }
        }
        return;
    }

    __shared__ int cur[NBKT];
    for (int i = tid; i < NBKT; i += BTHR)
        cur[i] = i * BKTSTRIDE + b * SUBCAP;       // absolute slot cursor
    __syncthreads();

    // Each block owns exactly CHUNK=6400 consecutive edge slots; E is a
    // multiple of 6400 so the d<E split is block-uniform.
    int lo = b * CHUNK;
    int cofs = (lo >= E) ? -E : E;
    #pragma unroll 1
    for (int d0 = lo + (tid << 2); d0 < lo + CHUNK; d0 += BTHR * 4) {
        int4 r = *(const int4*)(idx + d0);
        int4 c = *(const int4*)(idx + d0 + cofs);
        int p0 = atomicAdd(&cur[r.x >> 8], 1);
        int p1 = atomicAdd(&cur[r.y >> 8], 1);
        int p2 = atomicAdd(&cur[r.z >> 8], 1);
        int p3 = atomicAdd(&cur[r.w >> 8], 1);
        binned[p0] = ((unsigned int)(r.x & 255) << 17) | (unsigned int)c.x;
        binned[p1] = ((unsigned int)(r.y & 255) << 17) | (unsigned int)c.y;
        binned[p2] = ((unsigned int)(r.z & 255) << 17) | (unsigned int)c.z;
        binned[p3] = ((unsigned int)(r.w & 255) << 17) | (unsigned int)c.w;
    }
    __syncthreads();

    for (int i = tid; i < NBKT; i += BTHR)
        cnts[i * NBLK_A + b] = cur[i] - (i * BKTSTRIDE + b * SUBCAP);
}

// ---------------------------------------------------------------------------
// B. Bucket accumulate v3. Reads its bucket's 500 sub-runs (2 lanes each,
//    exact lengths from cnts — no sentinels), counting-sorts by local node
//    into sedge (2 LDS atomics/edge), then atomic-free register
//    accumulation with 2 lanes/node x 16B gathers.
// ---------------------------------------------------------------------------
__global__ __launch_bounds__(1024, 2) void agg_kernel(
    const __half* __restrict__ xcon, const int* __restrict__ cnts,
    const unsigned int* __restrict__ binned, __half* __restrict__ agg) {
    __shared__ unsigned int sedge[CAP];   // 40 KB
    __shared__ int scnt[NPB];
    __shared__ int soff[NPB];
    int b = blockIdx.x, tid = threadIdx.x;
    if (tid < NPB) scnt[tid] = 0;
    __syncthreads();

    int sub = tid >> 1, l = tid & 1;      // 500 sub-runs, 2 lanes each
    int sc  = (sub < NBLK_A) ? cnts[b * NBLK_A + sub] : 0;
    unsigned int base = (unsigned int)b * BKTSTRIDE + (unsigned int)sub * SUBCAP;

    // pass 1: per-node counts
    for (int j = l; j < sc; j += 2)
        atomicAdd(&scnt[binned[base + j] >> 17], 1);
    __syncthreads();

    // pass 2: exclusive scan (Hillis-Steele over 256)
    if (tid < NPB) soff[tid] = scnt[tid];
    __syncthreads();
    for (int off = 1; off < NPB; off <<= 1) {
        int y = 0;
        if (tid < NPB && tid >= off) y = soff[tid - off];
        __syncthreads();
        if (tid < NPB) soff[tid] += y;
        __syncthreads();
    }
    if (tid < NPB) soff[tid] -= scnt[tid];
    __syncthreads();

    // pass 3: scatter into node-sorted sedge (L2/L3-hot re-read of sub-runs)
    for (int j = l; j < sc; j += 2) {
        unsigned int p = binned[base + j];
        int pos = atomicAdd(&soff[p >> 17], 1);
        sedge[pos] = p & 0x1FFFFu;
    }
    __syncthreads();

    // pass 4: accumulate, 2 lanes/node, 16B gathers from L2-resident xcon
    if (tid < 2 * NPB) {
        int nl = tid >> 1, q = tid & 1;
        int c  = scnt[nl];
        int s0 = soff[nl] - c;                 // soff advanced to row end
        float a0 = 0.f, a1 = 0.f, a2 = 0.f, a3 = 0.f;
        float a4 = 0.f, a5 = 0.f, a6 = 0.f, a7 = 0.f;
        #pragma unroll 2
        for (int k = 0; k < c; k++) {
            int col = (int)sedge[s0 + k];      // broadcast within pair
            uint4 raw = ((const uint4*)(xcon + (size_t)col * 16))[q];
            float2 f0 = __half22float2(*(const __half2*)&raw.x);
            float2 f1 = __half22float2(*(const __half2*)&raw.y);
            float2 f2 = __half22float2(*(const __half2*)&raw.z);
            float2 f3 = __half22float2(*(const __half2*)&raw.w);
            a0 += f0.x; a1 += f0.y; a2 += f1.x; a3 += f1.y;
            a4 += f2.x; a5 += f2.y; a6 += f3.x; a7 += f3.y;
        }
        int n = b * NPB + nl;
        if (n < N_NODES) {
            float inv = 1.0f / (float)max(c, 1);
            __half2 h0 = __floats2half2_rn(a0 * inv, a1 * inv);
            __half2 h1 = __floats2half2_rn(a2 * inv, a3 * inv);
            __half2 h2 = __floats2half2_rn(a4 * inv, a5 * inv);
            __half2 h3 = __floats2half2_rn(a6 * inv, a7 * inv);
            uint4 st;
            st.x = *(unsigned int*)&h0; st.y = *(unsigned int*)&h1;
            st.z = *(unsigned int*)&h2; st.w = *(unsigned int*)&h3;
            *(uint4*)(agg + (size_t)n * 16 + q * 8) = st;   // 16B/lane
        }
    }
}

// ---------------------------------------------------------------------------
// C. MLP (R9/R10-verified): fused two-phase, 8 waves per 64-node tile.
//    Phase A: wave ws computes h[k=ws*16..+15] (k wave-uniform -> W1t on the
//    scalar pipe), h-pairs f16 in LDS H2[kp][node]. Phase B: wave ws
//    computes outs o=ws*4..+3 from H2 + s_load'ed W2t. 12500 waves.
// ---------------------------------------------------------------------------
__global__ __launch_bounds__(512, 4) void mlp_kernel(
    const float* __restrict__ x, const __half* __restrict__ agg,
    const float* __restrict__ W1t, const float* __restrict__ b1,
    const float* __restrict__ W2t, const float* __restrict__ b2,
    float* __restrict__ out, int N) {
    __shared__ __half2 H2[64 * 64];   // [kp][node], 16 KB
    int tid  = threadIdx.x;
    int lane = tid & 63;
    int ws   = __builtin_amdgcn_readfirstlane(tid >> 6);
    int n    = blockIdx.x * 64 + lane;
    int nc   = min(n, N - 1);

    float comb[32];
    const float4* xr = (const float4*)(x + (size_t)nc * 32);
    #pragma unroll
    for (int c = 0; c < 4; c++) {
        float4 v = xr[c];
        comb[c*4+0] = v.x; comb[c*4+1] = v.y;
        comb[c*4+2] = v.z; comb[c*4+3] = v.w;
    }
    const __half2* ar = (const __half2*)(agg + (size_t)nc * 16);
    #pragma unroll
    for (int c = 0; c < 8; c++) {
        float2 f = __half22float2(ar[c]);
        comb[16 + 2*c]     = f.x;
        comb[16 + 2*c + 1] = f.y;
    }

    #pragma unroll
    for (int i = 0; i < 16; i += 2) {
        int k0 = ws * 16 + i;
        const float* w1a = W1t + k0 * 32;
        const float* w1b = w1a + 32;
        float ha = b1[k0], hb = b1[k0 + 1];
        #pragma unroll
        for (int c = 0; c < 32; c++) {
            ha = fmaf(comb[c], w1a[c], ha);
            hb = fmaf(comb[c], w1b[c], hb);
        }
        ha = fmaxf(ha, 0.f); hb = fmaxf(hb, 0.f);
        H2[(k0 >> 1) * 64 + lane] = __floats2half2_rn(ha, hb);
    }
    __syncthreads();

    int o0 = ws * 4;
    const float* w20 = W2t + (o0 + 0) * 128;
    const float* w21 = W2t + (o0 + 1) * 128;
    const float* w22 = W2t + (o0 + 2) * 128;
    const float* w23 = W2t + (o0 + 3) * 128;
    float acc0 = b2[o0+0], acc1 = b2[o0+1], acc2 = b2[o0+2], acc3 = b2[o0+3];
    #pragma unroll 8
    for (int kp = 0; kp < 64; kp++) {
        float2 h = __half22float2(H2[kp * 64 + lane]);
        int k0 = 2 * kp;
        acc0 = fmaf(h.x, w20[k0], acc0); acc0 = fmaf(h.y, w20[k0+1], acc0);
        acc1 = fmaf(h.x, w21[k0], acc1); acc1 = fmaf(h.y, w21[k0+1], acc1);
        acc2 = fmaf(h.x, w22[k0], acc2); acc2 = fmaf(h.y, w22[k0+1], acc2);
        acc3 = fmaf(h.x, w23[k0], acc3); acc3 = fmaf(h.y, w23[k0+1], acc3);
    }
    if (n < N) {
        float* op = out + (size_t)n * 32 + o0;
        op[0] = acc0; op[1] = acc1; op[2] = acc2; op[3] = acc3;
    }
}

extern "C" void kernel_launch(void* const* d_in, const int* in_sizes, int n_in,
                              void* d_out, int out_size, void* d_ws, size_t ws_size,
                              hipStream_t stream) {
    const float* x   = (const float*)d_in[0];
    const int*   idx = (const int*)d_in[1];
    const float* W1  = (const float*)d_in[2];
    const float* b1  = (const float*)d_in[3];
    const float* W2  = (const float*)d_in[4];
    const float* b2  = (const float*)d_in[5];
    float* out = (float*)d_out;

    const int E = in_sizes[1] / 2;     // 1,600,000
    const int total = 2 * E;           // 3,200,000

    // ws layout (~57.3 MB of the 256 MiB workspace):
    //   agg f16 3.2MB | xcon f16 3.2MB | W1t 16KB | W2t 16KB |
    //   cnts 391*500*4 = 782KB (padded) | binned 391*32000*4 = 50.05MB
    char* base = (char*)d_ws;
    __half*       agg    = (__half*)base;
    __half*       xcon   = (__half*)(base + 3203072);
    float*        W1t    = (float*)(base + 6406144);
    float*        W2t    = (float*)(base + 6422528);
    int*          cnts   = (int*)(base + 6438912);
    unsigned int* binned = (unsigned int*)(base + 7225344);

    int pack_blocks = (N_NODES * 4 + BTHR - 1) / BTHR;   // 782
    binfuse_kernel<<<NBLK_A + 1 + pack_blocks, BTHR, 0, stream>>>(
        idx, x, (__half2*)xcon, W1, W2, W1t, W2t,
        binned, cnts, CHUNK, total, E);
    agg_kernel<<<NBKT, 1024, 0, stream>>>(xcon, cnts, binned, agg);
    mlp_kernel<<<(N_NODES + 63) / 64, 512, 0, stream>>>(
        x, agg, W1t, b1, W2t, b2, out, N_NODES);
}

// Round 2
// 160.128 us; speedup vs baseline: 1.0956x; 1.0956x over previous
//
#include <hip/hip_runtime.h>
#include <hip/hip_bf16.h>
#include <hip/hip_fp16.h>

#define N_NODES  100000
#define N_RADIAL 16
#define N_CONICAL 16

#define NPB    256                                   // nodes per bucket
#define NBKT   ((N_NODES + NPB - 1) / NPB)           // 391 buckets
#define NBLK_A 256                                   // binfuse scatter blocks (R10 layout)
#define BTHR   512                                   // binfuse block threads
#define SUBCAP 96                                    // per-(block,bucket) sub-run cap
                                                     // mean 32, sigma 5.65 -> +11σ, P(ovf)~4e-20
#define BKTSTRIDE (NBLK_A * SUBCAP)                  // 24576 slots per bucket
#define CAP    10240                                 // compacted bucket cap in LDS (mean 8192 + 22σ)

// ---------------------------------------------------------------------------
// A. Fused bin+prep. Blocks 0..255: single-pass scatter into fixed-capacity
//    per-(block,bucket) sub-runs — 1 LDS cursor atomic + 1 line-dense write
//    per edge. R12: keep the R10 binned layout (256 blocks x SUBCAP 96 —
//    R11's 500x64 layout doubled agg's FETCH via sparse sub-runs) but take
//    the int4 edge loads: 4 independent atomic->store chains per thread
//    attack the latency-bound scatter tail (was VALUBusy 2.9%, Occ 22.9%).
//    Block 256: W1/W2 transposes. Blocks 257..: xcon f16 pack, one
//    float4 -> uint2 per thread.
// ---------------------------------------------------------------------------
__global__ __launch_bounds__(BTHR) void binfuse_kernel(
    const int* __restrict__ idx, const float* __restrict__ x,
    __half2* __restrict__ xcon2,
    const float* __restrict__ W1, const float* __restrict__ W2,
    float* __restrict__ W1t, float* __restrict__ W2t,
    unsigned int* __restrict__ binned, int* __restrict__ cnts,
    int chunk, int total, int E) {
    int b = blockIdx.x, tid = threadIdx.x;
    if (b >= NBLK_A) {
        int pb = b - NBLK_A;
        if (pb == 0) {                       // weight transposes (4096 each)
            for (int i = tid; i < 4096; i += BTHR) {
                int c = i >> 7, k = i & 127;
                W1t[k * 32 + c] = W1[i];     // W1[c][k] -> W1t[k][c]
                int kk = i >> 5, o = i & 31;
                W2t[o * 128 + kk] = W2[i];   // W2[k][o] -> W2t[o][k]
            }
        } else {                             // xcon pack: one float4 -> uint2/thread
            int t = (pb - 1) * BTHR + tid;
            if (t < N_NODES * 4) {
                int n = t >> 2, p = t & 3;
                float4 v = *((const float4*)(x + (size_t)n * 32 + 16) + p);
                __half2 h0 = __floats2half2_rn(v.x, v.y);
                __half2 h1 = __floats2half2_rn(v.z, v.w);
                uint2 st;
                st.x = *(unsigned int*)&h0; st.y = *(unsigned int*)&h1;
                *(uint2*)(xcon2 + 2 * t) = st;
            }
        }
        return;
    }

    __shared__ int cur[NBKT];
    for (int i = tid; i < NBKT; i += BTHR)
        cur[i] = i * BKTSTRIDE + b * SUBCAP;       // absolute slot cursor
    __syncthreads();

    // chunk = 12500: 4-divisible, and E/chunk = 128 -> the d<E split is
    // block-uniform, so cofs is wave-uniform and int4 loads never straddle.
    int lo = b * chunk;
    int cofs = (lo >= E) ? -E : E;
    const int4* rp = (const int4*)(idx + lo);
    const int4* cp = (const int4*)(idx + lo + cofs);
    int nq = chunk >> 2;                      // 3125 int4 quads per block
    #pragma unroll 1
    for (int q = tid; q < nq; q += BTHR) {
        int4 r = rp[q];
        int4 c = cp[q];
        int p0 = atomicAdd(&cur[r.x >> 8], 1);
        int p1 = atomicAdd(&cur[r.y >> 8], 1);
        int p2 = atomicAdd(&cur[r.z >> 8], 1);
        int p3 = atomicAdd(&cur[r.w >> 8], 1);
        binned[p0] = ((unsigned int)(r.x & 255) << 17) | (unsigned int)c.x;
        binned[p1] = ((unsigned int)(r.y & 255) << 17) | (unsigned int)c.y;
        binned[p2] = ((unsigned int)(r.z & 255) << 17) | (unsigned int)c.z;
        binned[p3] = ((unsigned int)(r.w & 255) << 17) | (unsigned int)c.w;
    }
    __syncthreads();

    for (int i = tid; i < NBKT; i += BTHR)
        cnts[i * NBLK_A + b] = cur[i] - (i * BKTSTRIDE + b * SUBCAP);
}

// ---------------------------------------------------------------------------
// B. Bucket accumulate v3 (byte-identical to the 158µs R10 version).
//    Reads its bucket's 256 sub-runs (4 lanes each, exact lengths from
//    cnts — no sentinels), counting-sorts by local node into sedge
//    (2 LDS atomics/edge), then atomic-free register accumulation with
//    2 lanes/node x 16B gathers from L2-resident xcon.
// ---------------------------------------------------------------------------
__global__ __launch_bounds__(1024, 2) void agg_kernel(
    const __half* __restrict__ xcon, const int* __restrict__ cnts,
    const unsigned int* __restrict__ binned, __half* __restrict__ agg) {
    __shared__ unsigned int sedge[CAP];   // 40 KB
    __shared__ int scnt[NPB];
    __shared__ int soff[NPB];
    int b = blockIdx.x, tid = threadIdx.x;
    if (tid < NPB) scnt[tid] = 0;
    __syncthreads();

    int sub = tid >> 2, l = tid & 3;
    int sc  = cnts[b * NBLK_A + sub];
    unsigned int base = (unsigned int)b * BKTSTRIDE + (unsigned int)sub * SUBCAP;

    // pass 1: per-node counts
    for (int j = l; j < sc; j += 4)
        atomicAdd(&scnt[binned[base + j] >> 17], 1);
    __syncthreads();

    // pass 2: exclusive scan (Hillis-Steele over 256)
    if (tid < NPB) soff[tid] = scnt[tid];
    __syncthreads();
    for (int off = 1; off < NPB; off <<= 1) {
        int y = 0;
        if (tid < NPB && tid >= off) y = soff[tid - off];
        __syncthreads();
        if (tid < NPB) soff[tid] += y;
        __syncthreads();
    }
    if (tid < NPB) soff[tid] -= scnt[tid];
    __syncthreads();

    // pass 3: scatter into node-sorted sedge (L2-hot re-read of sub-runs)
    for (int j = l; j < sc; j += 4) {
        unsigned int p = binned[base + j];
        int pos = atomicAdd(&soff[p >> 17], 1);
        sedge[pos] = p & 0x1FFFFu;
    }
    __syncthreads();

    // pass 4: accumulate, 2 lanes/node, 16B gathers from L2-resident xcon
    if (tid < 2 * NPB) {
        int nl = tid >> 1, q = tid & 1;
        int c  = scnt[nl];
        int s0 = soff[nl] - c;                 // soff advanced to row end
        float a0 = 0.f, a1 = 0.f, a2 = 0.f, a3 = 0.f;
        float a4 = 0.f, a5 = 0.f, a6 = 0.f, a7 = 0.f;
        #pragma unroll 2
        for (int k = 0; k < c; k++) {
            int col = (int)sedge[s0 + k];      // broadcast within pair
            uint4 raw = ((const uint4*)(xcon + (size_t)col * 16))[q];
            float2 f0 = __half22float2(*(const __half2*)&raw.x);
            float2 f1 = __half22float2(*(const __half2*)&raw.y);
            float2 f2 = __half22float2(*(const __half2*)&raw.z);
            float2 f3 = __half22float2(*(const __half2*)&raw.w);
            a0 += f0.x; a1 += f0.y; a2 += f1.x; a3 += f1.y;
            a4 += f2.x; a5 += f2.y; a6 += f3.x; a7 += f3.y;
        }
        int n = b * NPB + nl;
        if (n < N_NODES) {
            float inv = 1.0f / (float)max(c, 1);
            __half2 h0 = __floats2half2_rn(a0 * inv, a1 * inv);
            __half2 h1 = __floats2half2_rn(a2 * inv, a3 * inv);
            __half2 h2 = __floats2half2_rn(a4 * inv, a5 * inv);
            __half2 h3 = __floats2half2_rn(a6 * inv, a7 * inv);
            uint4 st;
            st.x = *(unsigned int*)&h0; st.y = *(unsigned int*)&h1;
            st.z = *(unsigned int*)&h2; st.w = *(unsigned int*)&h3;
            *(uint4*)(agg + (size_t)n * 16 + q * 8) = st;   // 16B/lane
        }
    }
}

// ---------------------------------------------------------------------------
// C. MLP (R9/R10-verified): fused two-phase, 8 waves per 64-node tile.
//    Phase A: wave ws computes h[k=ws*16..+15] (k wave-uniform -> W1t on the
//    scalar pipe), h-pairs f16 in LDS H2[kp][node]. Phase B: wave ws
//    computes outs o=ws*4..+3 from H2 + s_load'ed W2t. 12500 waves.
// ---------------------------------------------------------------------------
__global__ __launch_bounds__(512, 4) void mlp_kernel(
    const float* __restrict__ x, const __half* __restrict__ agg,
    const float* __restrict__ W1t, const float* __restrict__ b1,
    const float* __restrict__ W2t, const float* __restrict__ b2,
    float* __restrict__ out, int N) {
    __shared__ __half2 H2[64 * 64];   // [kp][node], 16 KB
    int tid  = threadIdx.x;
    int lane = tid & 63;
    int ws   = __builtin_amdgcn_readfirstlane(tid >> 6);
    int n    = blockIdx.x * 64 + lane;
    int nc   = min(n, N - 1);

    float comb[32];
    const float4* xr = (const float4*)(x + (size_t)nc * 32);
    #pragma unroll
    for (int c = 0; c < 4; c++) {
        float4 v = xr[c];
        comb[c*4+0] = v.x; comb[c*4+1] = v.y;
        comb[c*4+2] = v.z; comb[c*4+3] = v.w;
    }
    const __half2* ar = (const __half2*)(agg + (size_t)nc * 16);
    #pragma unroll
    for (int c = 0; c < 8; c++) {
        float2 f = __half22float2(ar[c]);
        comb[16 + 2*c]     = f.x;
        comb[16 + 2*c + 1] = f.y;
    }

    #pragma unroll
    for (int i = 0; i < 16; i += 2) {
        int k0 = ws * 16 + i;
        const float* w1a = W1t + k0 * 32;
        const float* w1b = w1a + 32;
        float ha = b1[k0], hb = b1[k0 + 1];
        #pragma unroll
        for (int c = 0; c < 32; c++) {
            ha = fmaf(comb[c], w1a[c], ha);
            hb = fmaf(comb[c], w1b[c], hb);
        }
        ha = fmaxf(ha, 0.f); hb = fmaxf(hb, 0.f);
        H2[(k0 >> 1) * 64 + lane] = __floats2half2_rn(ha, hb);
    }
    __syncthreads();

    int o0 = ws * 4;
    const float* w20 = W2t + (o0 + 0) * 128;
    const float* w21 = W2t + (o0 + 1) * 128;
    const float* w22 = W2t + (o0 + 2) * 128;
    const float* w23 = W2t + (o0 + 3) * 128;
    float acc0 = b2[o0+0], acc1 = b2[o0+1], acc2 = b2[o0+2], acc3 = b2[o0+3];
    #pragma unroll 8
    for (int kp = 0; kp < 64; kp++) {
        float2 h = __half22float2(H2[kp * 64 + lane]);
        int k0 = 2 * kp;
        acc0 = fmaf(h.x, w20[k0], acc0); acc0 = fmaf(h.y, w20[k0+1], acc0);
        acc1 = fmaf(h.x, w21[k0], acc1); acc1 = fmaf(h.y, w21[k0+1], acc1);
        acc2 = fmaf(h.x, w22[k0], acc2); acc2 = fmaf(h.y, w22[k0+1], acc2);
        acc3 = fmaf(h.x, w23[k0], acc3); acc3 = fmaf(h.y, w23[k0+1], acc3);
    }
    if (n < N) {
        float* op = out + (size_t)n * 32 + o0;
        op[0] = acc0; op[1] = acc1; op[2] = acc2; op[3] = acc3;
    }
}

extern "C" void kernel_launch(void* const* d_in, const int* in_sizes, int n_in,
                              void* d_out, int out_size, void* d_ws, size_t ws_size,
                              hipStream_t stream) {
    const float* x   = (const float*)d_in[0];
    const int*   idx = (const int*)d_in[1];
    const float* W1  = (const float*)d_in[2];
    const float* b1  = (const float*)d_in[3];
    const float* W2  = (const float*)d_in[4];
    const float* b2  = (const float*)d_in[5];
    float* out = (float*)d_out;

    const int E = in_sizes[1] / 2;     // 1,600,000
    const int total = 2 * E;           // 3,200,000
    const int chunk = (total + NBLK_A - 1) / NBLK_A;   // 12,500

    // ws layout (~45.3 MB of the 256 MiB workspace):
    //   agg f16 3.2MB | xcon f16 3.2MB | W1t 16KB | W2t 16KB |
    //   cnts 400KB | binned 391*24576*4 = 38.4MB
    char* base = (char*)d_ws;
    __half*       agg    = (__half*)base;
    __half*       xcon   = (__half*)(base + 3203072);
    float*        W1t    = (float*)(base + 6406144);
    float*        W2t    = (float*)(base + 6422528);
    int*          cnts   = (int*)(base + 6438912);
    unsigned int* binned = (unsigned int*)(base + 6839296);

    int pack_blocks = (N_NODES * 4 + BTHR - 1) / BTHR;   // 782
    binfuse_kernel<<<NBLK_A + 1 + pack_blocks, BTHR, 0, stream>>>(
        idx, x, (__half2*)xcon, W1, W2, W1t, W2t,
        binned, cnts, chunk, total, E);
    agg_kernel<<<NBKT, 1024, 0, stream>>>(xcon, cnts, binned, agg);
    mlp_kernel<<<(N_NODES + 63) / 64, 512, 0, stream>>>(
        x, agg, W1t, b1, W2t, b2, out, N_NODES);
}